// Round 14
// baseline (2420.862 us; speedup 1.0000x reference)
//
#include <hip/hip_runtime.h>
#include <stdint.h>

// LSTM: B=256, T=1024, I=64, H=256, O=1. fp32 in/out, bf16 MFMA internally.
//
// Round-25 = R24 (2270us; == R11 within noise) with ONE change: publishes
// go out as global_atomic_swap_x2 sc1 (no-return, device scope) instead of
// plain relaxed agent stores. Rationale: R24 refuted the s_sleep-wakeup
// theory (load-paced poll == sleep poll); step time is insensitive to
// pacing, fan-in, overlap, spill, topology. The one untested serial term
// is PRODUCER STORE VISIBILITY: plain sc0sc1 stores may drain lazily
// toward MALL (~1-2k cy), a lag inherited by every detect and invisible to
// all prior experiments (all used the same store). Atomics execute AT the
// MALL on arrival (no lazy drain; one-way travel only). R13 proved swap
// publishes are CORRECT (its regression was the consumer-side RMW polling,
// 9.7GB WRITE_SIZE - consumers here keep cheap relaxed loads).
// Per-address total order at MALL preserves the 8B {payload,tag} protocol.
// fc reads MALL-resident units with agent loads (R13-verified pattern).
//
// Carried from R24 (verified): E1 load-latency-paced quiet poll (no
// s_sleep; 1 dependent 32B sweep per ~RT per unsatisfied lane; satisfied
// lanes stop issuing; SENT_CAP dead-latch => wrong-answer-not-hang).
// E2 own-slice shortcut (own 32 hid written to LDS locally; 32 own-threads
// skip polling; 1024->896 polled units). E3 acc-init + x-part MFMAs
// hoisted into the poll shadow.
//
// Structure (R3/R9/R11 proven): 256 blocks = 32 batch-groups (8 batches) x
// 8 gate-slices (128 gate rows). Weights register-resident as bf16 MFMA
// B-fragments. h published as 8B single-copy-atomic units {2xbf16 h, tag=
// step}; consumers poll tags directly - no fences, no flags, no producer
// drain. Parity-reuse safety: tag-t units are only overwritten at end of
// step t+1, which needs all peers' poll(t) complete. Tag poison 0xAAAAAAAA
// never equals live tags 1..1024 => no ws init.

#define T_ 1024
#define I_ 64
#define H_ 256
#define NSLICE 8
#define NGROUP 32
#define MB 8      /* batches per group  */
#define HB 32     /* hidden units per block */
#define HROW 272  /* padded h_lds row (ushorts), 544 B = 34 x 16 B */

#define UNITS_PER_GROUP 1024                       /* 8B units per step */
#define UNITS_PER_PARITY (NGROUP * UNITS_PER_GROUP)
#define SENT_CAP (1 << 16)   /* dead-latch: ~64k load-paced sweeps (~25ms) */

typedef float floatx4 __attribute__((ext_vector_type(4)));
typedef __bf16 bf16x8 __attribute__((ext_vector_type(8)));
typedef unsigned short ushortx8 __attribute__((ext_vector_type(8)));
typedef unsigned int uintx4 __attribute__((ext_vector_type(4)));
typedef unsigned int uint32;
typedef unsigned long long u64;

__device__ __forceinline__ float bf2f(uint32 u16) {
  uint32 u = u16 << 16;
  return __builtin_bit_cast(float, u);
}
__device__ __forceinline__ bf16x8 packbf8(floatx4 a, floatx4 b) {
  bf16x8 r;
  r[0] = (__bf16)a[0]; r[1] = (__bf16)a[1];
  r[2] = (__bf16)a[2]; r[3] = (__bf16)a[3];
  r[4] = (__bf16)b[0]; r[5] = (__bf16)b[1];
  r[6] = (__bf16)b[2]; r[7] = (__bf16)b[3];
  return r;
}
__device__ __forceinline__ float fast_sig(float v) {
  return 1.0f / (1.0f + __expf(-v));
}
__device__ __forceinline__ float fast_tanh(float v) {
  float e = __expf(2.0f * v);
  return 1.0f - 2.0f / (e + 1.0f);
}
__device__ __forceinline__ u64 aload64(const u64* p) {
  return __hip_atomic_load(p, __ATOMIC_RELAXED, __HIP_MEMORY_SCOPE_AGENT);
}
// no-return device-scope swap: executes at MALL on arrival (no lazy drain,
// no ack on the critical path). sc1 = device scope; no sc0 = no return.
__device__ __forceinline__ void pub64(u64* p, u64 v) {
  asm volatile("global_atomic_swap_x2 %0, %1, off sc1" ::"v"(p), "v"(v)
               : "memory");
}

__global__ __launch_bounds__(256, 1) void lstm_main(
    const float* __restrict__ x, const float* __restrict__ W_ih,
    const float* __restrict__ W_hh, const float* __restrict__ b_ih,
    const float* __restrict__ b_hh, u64* __restrict__ units) {
  const int tid = threadIdx.x;
  const int bid = blockIdx.x;
  const int s = bid >> 5;     // slice 0..7  (bid%8 == g%8 -> spread XCDs)
  const int g = bid & 31;     // group 0..31
  const int w = tid >> 6;     // wave id == gate type (i,f,g,o)
  const int lane = tid & 63;
  const int ln = lane & 15;   // MFMA n / A m
  const int lk = lane >> 4;   // MFMA k-subgroup (8 elems each)

  __shared__ float xch[4][2][16][8];                     // [gate][j][n][m]
  __shared__ __align__(16) unsigned short h_lds[MB][HROW];

  // zero h_lds (h_0 = 0 for t=0; also clears pad)
  {
    uint32* p = (uint32*)&h_lds[0][0];
    for (int i = tid; i < MB * HROW / 2; i += 256) p[i] = 0u;
  }

  // ---- preload weight B-fragments (bf16) + bias, once ----
  bf16x8 wf[2][10];
  float bias[2];
#pragma unroll
  for (int j = 0; j < 2; ++j) {
    const int row = w * 256 + s * HB + j * 16 + ln;
    bias[j] = b_ih[row] + b_hh[row];
#pragma unroll
    for (int kc = 0; kc < 10; ++kc) {
      const int kk = kc * 32 + lk * 8;
      const float* src = (kk < I_) ? (W_ih + (size_t)row * I_ + kk)
                                   : (W_hh + (size_t)row * H_ + (kk - I_));
      floatx4 f0 = *(const floatx4*)src;
      floatx4 f1 = *(const floatx4*)(src + 4);
      wf[j][kc] = packbf8(f0, f1);
    }
  }

  const int mb = ln & 7;                       // batch row (m>=8 duplicates)
  const float* xrow = x + ((size_t)(g * MB + mb)) * T_ * I_;
  // update-phase roles
  const int um = tid >> 5;                     // 0..7 batch
  const int uh = tid & 31;                     // 0..31 hidden local
  const int uj = uh >> 4, un = uh & 15;
  float c_reg = 0.0f;

  // E2: threads whose 4 poll units are ALL this block's own publishes
  // ((tid&31)>>2 == s <=> unit dwords in [s*16, s*16+16)) skip the poll;
  // those h_lds cols are written locally at update time instead.
  const bool ownthr = (((tid & 31) >> 2) == s);

  const size_t gbase = (size_t)g * UNITS_PER_GROUP;

  __syncthreads();

#pragma unroll 1
  for (int t = 0; t < T_; ++t) {
    // x loads issued first so they overlap the poll
    floatx4 xf0, xf1, xf2, xf3;
    {
      const float* src = xrow + t * I_ + lk * 8;
      xf0 = *(const floatx4*)(src);
      xf1 = *(const floatx4*)(src + 4);
      xf2 = *(const floatx4*)(src + 32);
      xf3 = *(const floatx4*)(src + 36);
    }

    // issue first poll probes BEFORE the x-part MFMAs (E3 overlap)
    const u64* up =
        units + (size_t)(t & 1) * UNITS_PER_PARITY + gbase + tid * 4;
    u64 v0 = 0, v1 = 0, v2 = 0, v3 = 0;
    const bool polling = (t > 0) && !ownthr;
    if (polling) {
      v0 = aload64(up + 0);
      v1 = aload64(up + 1);
      v2 = aload64(up + 2);
      v3 = aload64(up + 3);
    }

    // ---- E3: acc init + x-part MFMAs (no h dependency, poll shadow) ----
    bf16x8 a0 = packbf8(xf0, xf1);
    bf16x8 a1 = packbf8(xf2, xf3);
    floatx4 acc[2];
    acc[0] = (floatx4){bias[0], bias[0], bias[0], bias[0]};
    acc[1] = (floatx4){bias[1], bias[1], bias[1], bias[1]};
    acc[0] = __builtin_amdgcn_mfma_f32_16x16x32_bf16(a0, wf[0][0], acc[0],
                                                     0, 0, 0);
    acc[1] = __builtin_amdgcn_mfma_f32_16x16x32_bf16(a0, wf[1][0], acc[1],
                                                     0, 0, 0);
    acc[0] = __builtin_amdgcn_mfma_f32_16x16x32_bf16(a1, wf[0][1], acc[0],
                                                     0, 0, 0);
    acc[1] = __builtin_amdgcn_mfma_f32_16x16x32_bf16(a1, wf[1][1], acc[1],
                                                     0, 0, 0);

    if (t > 0) {
      // ---- E1: load-latency-paced quiet poll (no s_sleep). Payload
      // captured in the detecting sweep. SENT_CAP => no hang.
      bool ok = !polling || (((uint32)(v0 >> 32) == (uint32)t) &
                            ((uint32)(v1 >> 32) == (uint32)t) &
                            ((uint32)(v2 >> 32) == (uint32)t) &
                            ((uint32)(v3 >> 32) == (uint32)t));
      int it = 0;
      while (!__all(ok) && ++it < SENT_CAP) {
        if (!ok) {
          v0 = aload64(up + 0);
          v1 = aload64(up + 1);
          v2 = aload64(up + 2);
          v3 = aload64(up + 3);
          ok = ((uint32)(v0 >> 32) == (uint32)t) &
               ((uint32)(v1 >> 32) == (uint32)t) &
               ((uint32)(v2 >> 32) == (uint32)t) &
               ((uint32)(v3 >> 32) == (uint32)t);
        }
      }
      if (polling) {
        uintx4 d;
        d[0] = (uint32)v0; d[1] = (uint32)v1;
        d[2] = (uint32)v2; d[3] = (uint32)v3;
        // unit u = m*128 + dword; tid*4 = (tid>>5)*128 + (tid&31)*4
        uint32* dst = (uint32*)&h_lds[tid >> 5][0] + (tid & 31) * 4;
        *(uintx4*)dst = d;  // 16B aligned
      }
    }
    __syncthreads();  // S1: h_lds ready (capture + own-local from t-1)

    // ---- h-part MFMAs: kc 2..9 from h_lds ----
    const unsigned short* hrow = &h_lds[mb][0];
#pragma unroll
    for (int kc = 2; kc < 10; ++kc) {
      bf16x8 a = __builtin_bit_cast(
          bf16x8, *(const ushortx8*)(hrow + (kc - 2) * 32 + lk * 8));
      acc[0] = __builtin_amdgcn_mfma_f32_16x16x32_bf16(a, wf[0][kc], acc[0],
                                                       0, 0, 0);
      acc[1] = __builtin_amdgcn_mfma_f32_16x16x32_bf16(a, wf[1][kc], acc[1],
                                                       0, 0, 0);
    }

    // ---- nonlinearity (wave-uniform branch) + LDS exchange ----
#pragma unroll
    for (int j = 0; j < 2; ++j) {
      floatx4 v = acc[j];
      if (w == 2) {
        v[0] = fast_tanh(v[0]); v[1] = fast_tanh(v[1]);
        v[2] = fast_tanh(v[2]); v[3] = fast_tanh(v[3]);
      } else {
        v[0] = fast_sig(v[0]); v[1] = fast_sig(v[1]);
        v[2] = fast_sig(v[2]); v[3] = fast_sig(v[3]);
      }
      if (lk < 2) {  // valid m rows 0..7 live in lanes 0..31, m = lk*4+reg
        *(floatx4*)&xch[w][j][ln][lk * 4] = v;
      }
    }
    __syncthreads();  // S2: gates ready

    // ---- c/h update: thread = (um, uh) ----
    float ig = xch[0][uj][un][um];
    float fg = xch[1][uj][un][um];
    float gg = xch[2][uj][un][um];
    float og = xch[3][uj][un][um];
    c_reg = fg * c_reg + ig * gg;
    float hv = og * fast_tanh(c_reg);

    // pair-pack via shfl; publish 8B unit {h pair, tag t+1} as a
    // no-return MALL atomic (visibility on arrival); E2: also write the
    // pair locally so next step's MFMA reads it from LDS.
    unsigned short hb = __builtin_bit_cast(unsigned short, (__bf16)hv);
    int pv = __shfl_xor((int)hb, 1);
    if ((uh & 1) == 0) {
      uint32 dword = (uint32)hb | ((uint32)(unsigned short)pv << 16);
      u64 val = (u64)dword | ((u64)(uint32)(t + 1) << 32);
      u64* dst = units + (size_t)((t + 1) & 1) * UNITS_PER_PARITY + gbase +
                 (um * 128 + s * 16 + (uh >> 1));
      pub64(dst, val);
      // own-slice local write (read after S1(t+1); disjoint from capture)
      *(uint32*)&h_lds[um][2 * (s * 16 + (uh >> 1))] = dword;
    }
  }
}

// out[b] = dot(h_T[b], fc_w) + fc_b. Final h = tag-1024 units in parity 0
// ((1023+1)&1 == 0). Atomic-published data lives at the MALL; agent loads
// read it coherently across replays.
__global__ void lstm_fc(const u64* __restrict__ units,
                        const float* __restrict__ fc_w,
                        const float* __restrict__ fc_b,
                        float* __restrict__ out) {
  const int b = threadIdx.x;
  const int g = b >> 3, m = b & 7;
  const u64* base = units + (size_t)g * UNITS_PER_GROUP + m * 128;
  float sum = fc_b[0];
#pragma unroll 8
  for (int d = 0; d < 128; ++d) {
    u64 v = aload64(base + d);
    uint32 lo = (uint32)v;
    sum += bf2f(lo & 0xffffu) * fc_w[2 * d] + bf2f(lo >> 16) * fc_w[2 * d + 1];
  }
  out[b] = sum;
}

extern "C" void kernel_launch(void* const* d_in, const int* in_sizes, int n_in,
                              void* d_out, int out_size, void* d_ws,
                              size_t ws_size, hipStream_t stream) {
  const float* x    = (const float*)d_in[0];
  const float* W_ih = (const float*)d_in[1];
  const float* W_hh = (const float*)d_in[2];
  const float* b_ih = (const float*)d_in[3];
  const float* b_hh = (const float*)d_in[4];
  const float* fc_w = (const float*)d_in[5];
  const float* fc_b = (const float*)d_in[6];
  float* out = (float*)d_out;

  u64* units = (u64*)d_ws;  // 2 parities x 32 groups x 1024 units x 8B = 512KB
  // tag poison 0xAAAAAAAA != any live tag (1..1024) => no init needed.

  lstm_main<<<dim3(NGROUP * NSLICE), dim3(256), 0, stream>>>(
      x, W_ih, W_hh, b_ih, b_hh, units);
  lstm_fc<<<dim3(1), dim3(256), 0, stream>>>(units, fc_w, fc_b, out);
}